// Round 1
// baseline (421.397 us; speedup 1.0000x reference)
//
#include <hip/hip_runtime.h>

// BinaryDense: out = sign(x) @ sign(w), x[8192,4096] f32, w[4096,4096] f32, out f32.
// Strategy: pack signs to int8 {-1,0,+1} (exact, handles sign(0)=0), then i8 MFMA GEMM.

#define M_DIM 8192
#define K_DIM 4096
#define N_DIM 4096

typedef int v4i  __attribute__((ext_vector_type(4)));
typedef int v16i __attribute__((ext_vector_type(16)));

typedef __attribute__((address_space(3))) void lds_void_t;
typedef __attribute__((address_space(1))) void g_void_t;

__device__ __forceinline__ signed char sgn8(float x) {
    return (signed char)((x > 0.0f) - (x < 0.0f));
}

// ---- pack x: fp32 -> int8 sign, identity layout. 16 elems/thread ----
__global__ __launch_bounds__(256) void pack_sign_kernel(const float* __restrict__ in,
                                                        signed char* __restrict__ out) {
    size_t i = (size_t)(blockIdx.x * 256u + threadIdx.x) * 16u;
    float tmp[16];
    *(float4*)(tmp + 0)  = *(const float4*)(in + i + 0);
    *(float4*)(tmp + 4)  = *(const float4*)(in + i + 4);
    *(float4*)(tmp + 8)  = *(const float4*)(in + i + 8);
    *(float4*)(tmp + 12) = *(const float4*)(in + i + 12);
    union { signed char c[16]; int4 v; } u;
#pragma unroll
    for (int j = 0; j < 16; ++j) u.c[j] = sgn8(tmp[j]);
    *(int4*)(out + i) = u.v;
}

// ---- pack wT: w[k][n] fp32 -> wT[n][k] int8, 64x64 tiles through LDS ----
__global__ __launch_bounds__(256) void pack_wT_kernel(const float* __restrict__ w,
                                                      signed char* __restrict__ wT) {
    __shared__ signed char sT[64 * 68];  // sT[r(k)][c(n)], stride 68 to spread banks
    const int t  = threadIdx.x;
    const int n0 = blockIdx.x * 64;
    const int k0 = blockIdx.y * 64;

    const int cq = t & 15;   // n-quad within tile
    const int r0 = t >> 4;   // k-row within tile (0..15)
#pragma unroll
    for (int p = 0; p < 4; ++p) {
        int r = r0 + 16 * p;
        float4 f = *(const float4*)(w + (size_t)(k0 + r) * N_DIM + n0 + cq * 4);
        char4 c;
        c.x = sgn8(f.x); c.y = sgn8(f.y); c.z = sgn8(f.z); c.w = sgn8(f.w);
        *(char4*)(sT + r * 68 + cq * 4) = c;
    }
    __syncthreads();

    const int n  = t >> 2;   // 0..63
    const int kq = t & 3;    // 16-byte chunk of k
    union { signed char c[16]; int4 v; } u;
#pragma unroll
    for (int j = 0; j < 16; ++j) u.c[j] = sT[(kq * 16 + j) * 68 + n];
    *(int4*)(wT + (size_t)(n0 + n) * K_DIM + k0 + kq * 16) = u.v;
}

// ---- i8 MFMA GEMM: C[M,N] = A[M,K] * B[N,K]^T (B given N-major = wT) ----
// 128x128 tile / block, BK=64, 4 waves (2x2), each wave 2x2 of 32x32x32 mfma.
__global__ __launch_bounds__(256) void bgemm_kernel(const signed char* __restrict__ A,
                                                    const signed char* __restrict__ B,
                                                    float* __restrict__ C) {
    __shared__ signed char sA[128 * 64];
    __shared__ signed char sB[128 * 64];

    const int tid  = threadIdx.x;
    const int lane = tid & 63;
    const int wave = tid >> 6;
    const int wm   = wave >> 1;   // 0..1
    const int wn   = wave & 1;    // 0..1
    const int l31  = lane & 31;
    const int lhi  = lane >> 5;   // 0..1

    const int m0 = blockIdx.y * 128;
    const int n0 = blockIdx.x * 128;

    v16i acc[2][2] = {};

    // Staging addresses. LDS granule g (16B) holds global chunk
    // (row m = g>>2, kchunk kc = (g&3) ^ ((m>>1)&3))  -- XOR swizzle kills
    // ds_read_b128 bank conflicts in the compute phase.
    const signed char* gA[2];
    const signed char* gB[2];
    int ldsOff[2];
#pragma unroll
    for (int i = 0; i < 2; ++i) {
        int g  = tid + i * 256;          // 0..511
        int m  = g >> 2;                 // 0..127
        int kc = (g & 3) ^ ((m >> 1) & 3);
        gA[i] = A + (size_t)(m0 + m) * K_DIM + kc * 16;
        gB[i] = B + (size_t)(n0 + m) * K_DIM + kc * 16;
        ldsOff[i] = g * 16;
    }

    // Fragment LDS offsets (constant across K loop).
    // a-frag: A[m = wm*64+tm*32+l31][k = ks*32 + lhi*16 + 0..15]
    int offA[2][2], offB[2][2];  // [ks][tm/tn]
#pragma unroll
    for (int ks = 0; ks < 2; ++ks) {
#pragma unroll
        for (int tmn = 0; tmn < 2; ++tmn) {
            int mloc = wm * 64 + tmn * 32 + l31;
            int nloc = wn * 64 + tmn * 32 + l31;
            int kcm  = (ks * 2 + lhi) ^ ((mloc >> 1) & 3);
            int kcn  = (ks * 2 + lhi) ^ ((nloc >> 1) & 3);
            offA[ks][tmn] = mloc * 64 + kcm * 16;
            offB[ks][tmn] = nloc * 64 + kcn * 16;
        }
    }

    for (int kt = 0; kt < K_DIM / 64; ++kt) {
        const size_t koff = (size_t)kt * 64;
#pragma unroll
        for (int i = 0; i < 2; ++i) {
            __builtin_amdgcn_global_load_lds((g_void_t*)(gA[i] + koff),
                                             (lds_void_t*)(sA + ldsOff[i]), 16, 0, 0);
            __builtin_amdgcn_global_load_lds((g_void_t*)(gB[i] + koff),
                                             (lds_void_t*)(sB + ldsOff[i]), 16, 0, 0);
        }
        __syncthreads();  // staging visible

#pragma unroll
        for (int ks = 0; ks < 2; ++ks) {
            v4i a[2], b[2];
#pragma unroll
            for (int tm = 0; tm < 2; ++tm) a[tm] = *(const v4i*)(sA + offA[ks][tm]);
#pragma unroll
            for (int tn = 0; tn < 2; ++tn) b[tn] = *(const v4i*)(sB + offB[ks][tn]);
#pragma unroll
            for (int tm = 0; tm < 2; ++tm)
#pragma unroll
                for (int tn = 0; tn < 2; ++tn)
                    acc[tm][tn] = __builtin_amdgcn_mfma_i32_32x32x32_i8(
                        a[tm], b[tn], acc[tm][tn], 0, 0, 0);
        }
        __syncthreads();  // compute done before next overwrite
    }

    // Epilogue: C/D layout (32x32): col = lane&31, row = (r&3) + 8*(r>>2) + 4*lhi
#pragma unroll
    for (int tm = 0; tm < 2; ++tm) {
#pragma unroll
        for (int tn = 0; tn < 2; ++tn) {
            const int col  = n0 + wn * 64 + tn * 32 + l31;
            const int rowb = m0 + wm * 64 + tm * 32 + 4 * lhi;
#pragma unroll
            for (int r = 0; r < 16; ++r) {
                int row = rowb + (r & 3) + 8 * (r >> 2);
                C[(size_t)row * N_DIM + col] = (float)acc[tm][tn][r];
            }
        }
    }
}

extern "C" void kernel_launch(void* const* d_in, const int* in_sizes, int n_in,
                              void* d_out, int out_size, void* d_ws, size_t ws_size,
                              hipStream_t stream) {
    const float* x = (const float*)d_in[0];   // [8192, 4096]
    const float* w = (const float*)d_in[1];   // [4096, 4096]
    float* out = (float*)d_out;               // [8192, 4096]

    signed char* xq = (signed char*)d_ws;                       // 32 MB
    signed char* wq = xq + (size_t)M_DIM * K_DIM;               // 16 MB

    // pack x: 33,554,432 elems / 16 per thread / 256 per block = 8192 blocks
    pack_sign_kernel<<<dim3(M_DIM * K_DIM / (16 * 256)), dim3(256), 0, stream>>>(x, xq);
    // pack wT: 64x64 tiles
    pack_wT_kernel<<<dim3(N_DIM / 64, K_DIM / 64), dim3(256), 0, stream>>>(w, wq);
    // GEMM: grid (N/128, M/128)
    bgemm_kernel<<<dim3(N_DIM / 128, M_DIM / 128), dim3(256), 0, stream>>>(xq, wq, out);
}

// Round 2
// 328.029 us; speedup vs baseline: 1.2846x; 1.2846x over previous
//
#include <hip/hip_runtime.h>

// BinaryDense: out = sign(x) @ sign(w). x[8192,4096] f32, w[4096,4096] f32, out f32.
// Round 2: pack signs to FP4 e2m1 nibbles {-1,0,+1} = {0xA,0x0,0x2}, then
// MX-scaled fp4 MFMA (scales = 1.0). Exact: products in {-1,0,1}, f32 acc,
// |sum| <= 4096 << 2^24.

#define M_DIM 8192
#define K_DIM 4096
#define N_DIM 4096
#define KB2   (K_DIM / 2)   // packed bytes per row = 2048

typedef int   v4i  __attribute__((ext_vector_type(4)));
typedef int   v8i  __attribute__((ext_vector_type(8)));
typedef float v16f __attribute__((ext_vector_type(16)));

typedef __attribute__((address_space(3))) void lds_void_t;
typedef __attribute__((address_space(1))) void g_void_t;

__device__ __forceinline__ unsigned int nib4(float x) {
    // fp4 e2m1: +1.0 -> 0b0010, -1.0 -> 0b1010, 0 -> 0b0000
    return x > 0.0f ? 0x2u : (x < 0.0f ? 0xAu : 0x0u);
}

// ---- pack x: 4 floats -> 4 nibbles (one ushort) per thread, fully coalesced ----
__global__ __launch_bounds__(256) void pack_x4(const float* __restrict__ in,
                                               unsigned short* __restrict__ out) {
    size_t t = (size_t)blockIdx.x * 256 + threadIdx.x;
    float4 f = ((const float4*)in)[t];
    unsigned int v = nib4(f.x) | (nib4(f.y) << 4) | (nib4(f.z) << 8) | (nib4(f.w) << 12);
    out[t] = (unsigned short)v;
}

// ---- pack wT: w[k][n] f32 -> wq4[n][k/2] nibbles, 64k x 128n tiles via LDS ----
__global__ __launch_bounds__(256) void pack_w4(const float* __restrict__ w,
                                               unsigned char* __restrict__ wT) {
    __shared__ unsigned char sT[64][132];   // [k][n] nibble codes, pad to spread banks
    const int t  = threadIdx.x;
    const int n0 = blockIdx.x * 128;
    const int k0 = blockIdx.y * 64;

    const int cq = t & 31;   // float4 column
    const int r0 = t >> 5;   // 0..7
#pragma unroll
    for (int p = 0; p < 8; ++p) {
        int r = r0 + 8 * p;
        float4 f = *(const float4*)(w + (size_t)(k0 + r) * N_DIM + n0 + cq * 4);
        uchar4 c;
        c.x = (unsigned char)nib4(f.x);
        c.y = (unsigned char)nib4(f.y);
        c.z = (unsigned char)nib4(f.z);
        c.w = (unsigned char)nib4(f.w);
        *(uchar4*)(&sT[r][cq * 4]) = c;
    }
    __syncthreads();

    const int n  = t >> 1;   // 0..127
    const int kq = t & 1;    // 32-k chunk
    union { unsigned char b[16]; int4 v; } u;
#pragma unroll
    for (int j = 0; j < 16; ++j) {
        unsigned lo = sT[kq * 32 + 2 * j][n];
        unsigned hi = sT[kq * 32 + 2 * j + 1][n];
        u.b[j] = (unsigned char)(lo | (hi << 4));
    }
    *(int4*)(wT + (size_t)(n0 + n) * KB2 + (size_t)blockIdx.y * 32 + kq * 16) = u.v;
}

__device__ __forceinline__ v8i widen(v4i x) {
    v8i r;
    r[0] = x[0]; r[1] = x[1]; r[2] = x[2]; r[3] = x[3];
    r[4] = 0; r[5] = 0; r[6] = 0; r[7] = 0;
    return r;
}

// ---- fp4 MFMA GEMM: C[M,N] = A * B^T, A/B packed nibbles K-major ----
// 128x128 tile, BK=128 (64 bytes/row), 4 waves 2x2, each wave 2x2 of 32x32x64.
__global__ __launch_bounds__(256) void bgemm_fp4(const unsigned char* __restrict__ A,
                                                 const unsigned char* __restrict__ B,
                                                 float* __restrict__ C) {
    __shared__ unsigned char sA[128 * 64];
    __shared__ unsigned char sB[128 * 64];

    const int tid  = threadIdx.x;
    const int lane = tid & 63;
    const int wave = tid >> 6;
    const int wm   = wave >> 1;
    const int wn   = wave & 1;
    const int l31  = lane & 31;
    const int lhi  = lane >> 5;

    const int m0 = blockIdx.y * 128;
    const int n0 = blockIdx.x * 128;

    v16f acc[2][2] = {};

    // Staging: LDS granule g (16B) holds global (row m = g>>2, kchunk kc = (g&3)^((m>>1)&3)).
    const unsigned char* gA[2];
    const unsigned char* gB[2];
    int ldsOff[2];
#pragma unroll
    for (int i = 0; i < 2; ++i) {
        int g  = tid + i * 256;
        int m  = g >> 2;
        int kc = (g & 3) ^ ((m >> 1) & 3);
        gA[i] = A + (size_t)(m0 + m) * KB2 + kc * 16;
        gB[i] = B + (size_t)(n0 + m) * KB2 + kc * 16;
        ldsOff[i] = g * 16;
    }

    // Fragment offsets: for MFMA step ks, lane needs k in [ks*64 + lhi*32, +32) = granule ks*2+lhi.
    int offA[2][2], offB[2][2];
#pragma unroll
    for (int ks = 0; ks < 2; ++ks) {
#pragma unroll
        for (int tmn = 0; tmn < 2; ++tmn) {
            int mloc = wm * 64 + tmn * 32 + l31;
            int nloc = wn * 64 + tmn * 32 + l31;
            int kcm  = (ks * 2 + lhi) ^ ((mloc >> 1) & 3);
            int kcn  = (ks * 2 + lhi) ^ ((nloc >> 1) & 3);
            offA[ks][tmn] = mloc * 64 + kcm * 16;
            offB[ks][tmn] = nloc * 64 + kcn * 16;
        }
    }

    for (int kt = 0; kt < K_DIM / 128; ++kt) {
        const size_t koff = (size_t)kt * 64;   // 64 bytes = 128 k per iter
#pragma unroll
        for (int i = 0; i < 2; ++i) {
            __builtin_amdgcn_global_load_lds((g_void_t*)(gA[i] + koff),
                                             (lds_void_t*)(sA + ldsOff[i]), 16, 0, 0);
            __builtin_amdgcn_global_load_lds((g_void_t*)(gB[i] + koff),
                                             (lds_void_t*)(sB + ldsOff[i]), 16, 0, 0);
        }
        __syncthreads();

#pragma unroll
        for (int ks = 0; ks < 2; ++ks) {
            v4i a4[2], b4[2];
#pragma unroll
            for (int tm = 0; tm < 2; ++tm) a4[tm] = *(const v4i*)(sA + offA[ks][tm]);
#pragma unroll
            for (int tn = 0; tn < 2; ++tn) b4[tn] = *(const v4i*)(sB + offB[ks][tn]);
#pragma unroll
            for (int tm = 0; tm < 2; ++tm)
#pragma unroll
                for (int tn = 0; tn < 2; ++tn)
                    acc[tm][tn] = __builtin_amdgcn_mfma_scale_f32_32x32x64_f8f6f4(
                        widen(a4[tm]), widen(b4[tn]), acc[tm][tn],
                        4, 4,                  // cbsz=FP4, blgp=FP4
                        0, 0x7F7F7F7F,         // opsel_a, scale_a (e8m0 1.0)
                        0, 0x7F7F7F7F);        // opsel_b, scale_b
        }
        __syncthreads();
    }

    // Epilogue: C/D 32x32 layout: col = lane&31, row = (r&3) + 8*(r>>2) + 4*lhi
#pragma unroll
    for (int tm = 0; tm < 2; ++tm) {
#pragma unroll
        for (int tn = 0; tn < 2; ++tn) {
            const int col  = n0 + wn * 64 + tn * 32 + l31;
            const int rowb = m0 + wm * 64 + tm * 32 + 4 * lhi;
#pragma unroll
            for (int r = 0; r < 16; ++r) {
                int row = rowb + (r & 3) + 8 * (r >> 2);
                C[(size_t)row * N_DIM + col] = acc[tm][tn][r];
            }
        }
    }
}

extern "C" void kernel_launch(void* const* d_in, const int* in_sizes, int n_in,
                              void* d_out, int out_size, void* d_ws, size_t ws_size,
                              hipStream_t stream) {
    const float* x = (const float*)d_in[0];   // [8192, 4096]
    const float* w = (const float*)d_in[1];   // [4096, 4096]
    float* out = (float*)d_out;               // [8192, 4096]

    unsigned char* xq = (unsigned char*)d_ws;                 // 16 MB packed x
    unsigned char* wq = xq + (size_t)M_DIM * KB2;             // 8 MB packed wT

    pack_x4<<<dim3(M_DIM * K_DIM / 4 / 256), dim3(256), 0, stream>>>(x, (unsigned short*)xq);
    pack_w4<<<dim3(N_DIM / 128, K_DIM / 64), dim3(256), 0, stream>>>(w, wq);
    bgemm_fp4<<<dim3(N_DIM / 128, M_DIM / 128), dim3(256), 0, stream>>>(xq, wq, out);
}

// Round 3
// 326.377 us; speedup vs baseline: 1.2911x; 1.0051x over previous
//
#include <hip/hip_runtime.h>

// BinaryDense: out = sign(x) @ sign(w). x[8192,4096] f32, w[4096,4096] f32, out f32.
// fp4 e2m1 nibble encoding {-1,0,+1} = {0xA,0x0,0x2}; MX-scaled fp4 MFMA (scales=1.0).
// Round 3: AITER-style pipeline — buffer_load->VGPR->ds_write, double-buffered LDS,
// ONE barrier per K-iter; global-load latency hidden by same-iter compute.

#define M_DIM 8192
#define K_DIM 4096
#define N_DIM 4096
#define KB2   (K_DIM / 2)   // packed bytes per row = 2048
#define NK    (K_DIM / 128) // 32 K-iterations (BK=128 -> 64 bytes/row)
#define BUFB  (128 * 64)    // one LDS buffer = 8 KB

typedef int   v4i  __attribute__((ext_vector_type(4)));
typedef int   v8i  __attribute__((ext_vector_type(8)));
typedef float v16f __attribute__((ext_vector_type(16)));

__device__ __forceinline__ unsigned int nib4(float x) {
    // fp4 e2m1: +1.0 -> 0b0010, -1.0 -> 0b1010, 0 -> 0b0000
    return x > 0.0f ? 0x2u : (x < 0.0f ? 0xAu : 0x0u);
}

// ---- fused pack: blocks [0, 32768) pack x; blocks [32768, 34816) pack wT ----
__global__ __launch_bounds__(256) void pack_both(const float* __restrict__ x,
                                                 unsigned short* __restrict__ xq,
                                                 const float* __restrict__ w,
                                                 unsigned char* __restrict__ wT) {
    if (blockIdx.x < 32768u) {
        // pack x: 4 floats -> 4 nibbles (one ushort) per thread
        size_t t = (size_t)blockIdx.x * 256 + threadIdx.x;
        float4 f = ((const float4*)x)[t];
        unsigned int v = nib4(f.x) | (nib4(f.y) << 4) | (nib4(f.z) << 8) | (nib4(f.w) << 12);
        xq[t] = (unsigned short)v;
        return;
    }
    // pack wT: w[k][n] f32 -> wT[n][k/2] nibbles, 64k x 128n tile via LDS
    __shared__ unsigned char sT[64][132];
    const unsigned id = blockIdx.x - 32768u;
    const int t  = threadIdx.x;
    const int n0 = (int)(id & 31) * 128;
    const int kb = (int)(id >> 5);
    const int k0 = kb * 64;

    const int cq = t & 31;   // float4 column
    const int r0 = t >> 5;   // 0..7
#pragma unroll
    for (int p = 0; p < 8; ++p) {
        int r = r0 + 8 * p;
        float4 f = *(const float4*)(w + (size_t)(k0 + r) * N_DIM + n0 + cq * 4);
        uchar4 c;
        c.x = (unsigned char)nib4(f.x);
        c.y = (unsigned char)nib4(f.y);
        c.z = (unsigned char)nib4(f.z);
        c.w = (unsigned char)nib4(f.w);
        *(uchar4*)(&sT[r][cq * 4]) = c;
    }
    __syncthreads();

    const int n  = t >> 1;   // 0..127
    const int kq = t & 1;    // 32-k chunk
    union { unsigned char b[16]; int4 v; } u;
#pragma unroll
    for (int j = 0; j < 16; ++j) {
        unsigned lo = sT[kq * 32 + 2 * j][n];
        unsigned hi = sT[kq * 32 + 2 * j + 1][n];
        u.b[j] = (unsigned char)(lo | (hi << 4));
    }
    *(int4*)(wT + (size_t)(n0 + n) * KB2 + (size_t)kb * 32 + kq * 16) = u.v;
}

__device__ __forceinline__ v8i widen(v4i x) {
    v8i r;
    r[0] = x[0]; r[1] = x[1]; r[2] = x[2]; r[3] = x[3];
    r[4] = 0; r[5] = 0; r[6] = 0; r[7] = 0;
    return r;
}

// ---- fp4 MFMA GEMM: C[M,N] = A * B^T, A/B packed nibbles K-major ----
// 128x128 tile, BK=128, 4 waves 2x2, each wave 2x2 of 32x32x64 mfma.
// Double-buffered LDS, reg-staged loads, one barrier per K-iter.
__global__ __launch_bounds__(256) void bgemm_fp4(const unsigned char* __restrict__ A,
                                                 const unsigned char* __restrict__ B,
                                                 float* __restrict__ C) {
    __shared__ unsigned char sA[2 * BUFB];
    __shared__ unsigned char sB[2 * BUFB];

    const int tid  = threadIdx.x;
    const int lane = tid & 63;
    const int wave = tid >> 6;
    const int wm   = wave >> 1;
    const int wn   = wave & 1;
    const int l31  = lane & 31;
    const int lhi  = lane >> 5;

    const int m0 = blockIdx.y * 128;
    const int n0 = blockIdx.x * 128;

    v16f acc[2][2] = {};

    // Staging: LDS granule g (16B) holds global (row m = g>>2, kchunk kc = (g&3)^((m>>1)&3)).
    const unsigned char* gA[2];
    const unsigned char* gB[2];
    int ldsOff[2];
#pragma unroll
    for (int i = 0; i < 2; ++i) {
        int g  = tid + i * 256;
        int m  = g >> 2;
        int kc = (g & 3) ^ ((m >> 1) & 3);
        gA[i] = A + (size_t)(m0 + m) * KB2 + kc * 16;
        gB[i] = B + (size_t)(n0 + m) * KB2 + kc * 16;
        ldsOff[i] = g * 16;
    }

    // Fragment offsets: MFMA step ks, lane needs k-granule ks*2+lhi (XOR-swizzled).
    int offA[2][2], offB[2][2];
#pragma unroll
    for (int ks = 0; ks < 2; ++ks) {
#pragma unroll
        for (int tmn = 0; tmn < 2; ++tmn) {
            int mloc = wm * 64 + tmn * 32 + l31;
            int nloc = wn * 64 + tmn * 32 + l31;
            int kcm  = (ks * 2 + lhi) ^ ((mloc >> 1) & 3);
            int kcn  = (ks * 2 + lhi) ^ ((nloc >> 1) & 3);
            offA[ks][tmn] = mloc * 64 + kcm * 16;
            offB[ks][tmn] = nloc * 64 + kcn * 16;
        }
    }

    auto compute = [&](int bo) {
#pragma unroll
        for (int ks = 0; ks < 2; ++ks) {
            v4i a4[2], b4[2];
#pragma unroll
            for (int tm = 0; tm < 2; ++tm) a4[tm] = *(const v4i*)(sA + bo + offA[ks][tm]);
#pragma unroll
            for (int tn = 0; tn < 2; ++tn) b4[tn] = *(const v4i*)(sB + bo + offB[ks][tn]);
#pragma unroll
            for (int tm = 0; tm < 2; ++tm)
#pragma unroll
                for (int tn = 0; tn < 2; ++tn)
                    acc[tm][tn] = __builtin_amdgcn_mfma_scale_f32_32x32x64_f8f6f4(
                        widen(a4[tm]), widen(b4[tn]), acc[tm][tn],
                        4, 4,                  // cbsz=FP4, blgp=FP4
                        0, 0x7F7F7F7F,         // opsel_a, scale_a (e8m0 1.0)
                        0, 0x7F7F7F7F);        // opsel_b, scale_b
        }
    };

    v4i rA[2], rB[2];
    // Prologue: tile 0 -> buf0
#pragma unroll
    for (int i = 0; i < 2; ++i) { rA[i] = *(const v4i*)gA[i]; rB[i] = *(const v4i*)gB[i]; }
#pragma unroll
    for (int i = 0; i < 2; ++i) {
        *(v4i*)(sA + ldsOff[i]) = rA[i];
        *(v4i*)(sB + ldsOff[i]) = rB[i];
    }
    __syncthreads();

    for (int kt = 0; kt < NK - 1; ++kt) {
        const size_t koff = (size_t)(kt + 1) * 64;
        // issue next-tile loads (latency covered by compute below)
#pragma unroll
        for (int i = 0; i < 2; ++i) {
            rA[i] = *(const v4i*)(gA[i] + koff);
            rB[i] = *(const v4i*)(gB[i] + koff);
        }
        compute((kt & 1) * BUFB);
        const int bn = ((kt + 1) & 1) * BUFB;
#pragma unroll
        for (int i = 0; i < 2; ++i) {
            *(v4i*)(sA + bn + ldsOff[i]) = rA[i];
            *(v4i*)(sB + bn + ldsOff[i]) = rB[i];
        }
        __syncthreads();
    }
    compute(((NK - 1) & 1) * BUFB);

    // Epilogue: C/D 32x32 layout: col = lane&31, row = (r&3) + 8*(r>>2) + 4*lhi
    // Nontemporal: C is streamed once; keep packed operands resident in L2.
#pragma unroll
    for (int tm = 0; tm < 2; ++tm) {
#pragma unroll
        for (int tn = 0; tn < 2; ++tn) {
            const int col  = n0 + wn * 64 + tn * 32 + l31;
            const int rowb = m0 + wm * 64 + tm * 32 + 4 * lhi;
#pragma unroll
            for (int r = 0; r < 16; ++r) {
                int row = rowb + (r & 3) + 8 * (r >> 2);
                __builtin_nontemporal_store(acc[tm][tn][r], &C[(size_t)row * N_DIM + col]);
            }
        }
    }
}

extern "C" void kernel_launch(void* const* d_in, const int* in_sizes, int n_in,
                              void* d_out, int out_size, void* d_ws, size_t ws_size,
                              hipStream_t stream) {
    const float* x = (const float*)d_in[0];   // [8192, 4096]
    const float* w = (const float*)d_in[1];   // [4096, 4096]
    float* out = (float*)d_out;               // [8192, 4096]

    unsigned char* xq = (unsigned char*)d_ws;                 // 16 MB packed x
    unsigned char* wq = xq + (size_t)M_DIM * KB2;             // 8 MB packed wT

    // 32768 blocks pack x + 2048 blocks pack wT, one dispatch
    pack_both<<<dim3(32768 + 2048), dim3(256), 0, stream>>>(
        x, (unsigned short*)xq, w, wq);
    bgemm_fp4<<<dim3(N_DIM / 128, M_DIM / 128), dim3(256), 0, stream>>>(xq, wq, out);
}